// Round 5
// baseline (220.924 us; speedup 1.0000x reference)
//
#include <hip/hip_runtime.h>
#include <hip/hip_bf16.h>
#include <stdint.h>

#define B_ 2
#define S_ 2048
#define D_ 1024
#define H_ 16
#define HD_ 64
#define KJL 32
#define N3 3072
#define N2 2048

typedef __attribute__((ext_vector_type(8))) __bf16 bf16x8;
typedef __attribute__((ext_vector_type(4))) float floatx4;
typedef __attribute__((ext_vector_type(4))) short short4v;
typedef __attribute__((ext_vector_type(2))) unsigned int uint2v;

__device__ __forceinline__ unsigned short f2b(float x) {
  union { float f; unsigned u; } v; v.f = x;
  unsigned r = v.u + 0x7fffu + ((v.u >> 16) & 1u);
  return (unsigned short)(r >> 16);
}

// pack two floats to packed bf16 (round via +0x8000): hi<<16 | lo
__device__ __forceinline__ unsigned int pkbf(float lo, float hi) {
  union { float f; unsigned u; } a, b;
  a.f = lo; b.f = hi;
  return __builtin_amdgcn_perm(b.u + 0x8000u, a.u + 0x8000u, 0x07060302u);
}

__device__ __forceinline__ void async16(const void* g, void* l) {
  __builtin_amdgcn_global_load_lds((__attribute__((address_space(1))) void*)(g),
                                   (__attribute__((address_space(3))) void*)(l),
                                   16, 0, 0);
}

// ---------------- fp32 -> bf16 vectorized convert (n multiple of 4) ----------------
__global__ void cvt4_kernel(const float* __restrict__ in,
                            unsigned short* __restrict__ out, int n4) {
  int i = blockIdx.x * blockDim.x + threadIdx.x;
  int stride = gridDim.x * blockDim.x;
  for (; i < n4; i += stride) {
    float4 v = *(const float4*)(in + 4 * (size_t)i);
    short4v o = {(short)f2b(v.x), (short)f2b(v.y), (short)f2b(v.z), (short)f2b(v.w)};
    *(short4v*)(out + 4 * (size_t)i) = o;
  }
}

// ------- fp32 in[r][c] (row stride Cs) -> bf16 out[c][r] (row len R), 32x32 tiles -------
__global__ void tcvt_kernel(const float* __restrict__ in,
                            unsigned short* __restrict__ out, int R, int Cs) {
  __shared__ float t[32][33];
  int c0 = blockIdx.x * 32, r0 = blockIdx.y * 32;
  int tx = threadIdx.x, ty = threadIdx.y;
  for (int j = 0; j < 32; j += 8)
    t[ty + j][tx] = in[(size_t)(r0 + ty + j) * Cs + c0 + tx];
  __syncthreads();
  for (int j = 0; j < 32; j += 8)
    out[(size_t)(c0 + ty + j) * R + r0 + tx] = f2b(t[tx][ty + j]);
}

// ------- fused JL weights: Bt2 rows [0,512)=(Wq@Sp^T)^T*scaleQ, [512,1024)=(Wk@Sp^T)^T -------
// also bias2[n] = (b @ Sp^T) (scaled for Q). W_attn fp32 [1024][3072], Sp fp32 [32][64].
__global__ __launch_bounds__(256)
void wjl_kernel(const float* __restrict__ W_attn, const float* __restrict__ b_attn,
                const float* __restrict__ Sp, unsigned short* __restrict__ Bt2,
                float* __restrict__ bias2) {
  __shared__ float SpL[32 * 64];
  const int bid = blockIdx.x;          // 0..127
  const int part = bid >> 6;           // 0 = Q, 1 = K
  const int h = (bid >> 2) & 15;
  const int dc = bid & 3;
  const int tid = threadIdx.x;
  for (int i = tid; i < 32 * 64; i += 256) SpL[i] = Sp[i];
  __syncthreads();
  const float scale = part ? 1.0f : 0.125f * 1.44269504f;
  const int d = dc * 256 + tid;
  float w[64];
  const float* src = W_attn + (size_t)d * N3 + part * D_ + h * 64;
  for (int j = 0; j < 16; ++j) {
    float4 v = *(const float4*)&src[j * 4];
    w[j * 4 + 0] = v.x; w[j * 4 + 1] = v.y; w[j * 4 + 2] = v.z; w[j * 4 + 3] = v.w;
  }
  const int nbase = part * 512 + h * 32;
  for (int kjl = 0; kjl < 32; ++kjl) {
    float acc = 0.f;
    for (int hd = 0; hd < 64; ++hd) acc += w[hd] * SpL[kjl * 64 + hd];
    Bt2[(size_t)(nbase + kjl) * D_ + d] = f2b(acc * scale);
  }
  if (dc == 0 && tid < 32) {
    float acc = 0.f;
    for (int hd = 0; hd < 64; ++hd) acc += b_attn[part * D_ + h * 64 + hd] * SpL[tid * 64 + hd];
    bias2[nbase + tid] = acc * scale;
  }
}

// ---------------- fused qkv+JL GEMM: hB[4096,1024] @ Bt2^T -> Qjl/Kjl/Vc ----------------
// Bt2: [2048][1024] bf16 (rows 0..511 WqJl^T scaled, 512..1023 WkJl^T, 1024..2047 Wv^T)
// Qjl/Kjl: [BH][S][32] bf16; Vc: chunk-tiled [BH][S/32][64][32] bf16
__global__ __launch_bounds__(256, 2)
void qkv2_gemm_kernel(const unsigned short* __restrict__ A,
                      const unsigned short* __restrict__ Bt,
                      const float* __restrict__ b_attn,
                      const float* __restrict__ bias2,
                      unsigned short* __restrict__ Qjl,
                      unsigned short* __restrict__ Kjl,
                      unsigned short* __restrict__ Vc) {
  __shared__ __align__(16) unsigned short As[128 * 32];
  __shared__ __align__(16) unsigned short Bs[128 * 32];
  const int tid = threadIdx.x;
  const int lane = tid & 63, wv = tid >> 6;
  const int quad = lane >> 4, col = lane & 15;
  const int wm = wv >> 1, wn = wv & 1;
  const int m0 = blockIdx.y * 128, n0 = blockIdx.x * 128;

  floatx4 acc[4][4] = {};

  for (int kk = 0; kk < D_; kk += 32) {
    for (int it = 0; it < 2; ++it) {
      int c = it * 256 + tid;
      int row = c >> 2, k8 = (c & 3) << 3;
      async16(A + (size_t)(m0 + row) * D_ + kk + k8, &As[c * 8]);
      async16(Bt + (size_t)(n0 + row) * D_ + kk + k8, &Bs[c * 8]);
    }
    asm volatile("s_waitcnt vmcnt(0)" ::: "memory");
    __syncthreads();
    bf16x8 af[4], bfr[4];
    for (int mt = 0; mt < 4; ++mt)
      af[mt] = *(const bf16x8*)&As[(wm * 64 + mt * 16 + col) * 32 + quad * 8];
    for (int nt = 0; nt < 4; ++nt)
      bfr[nt] = *(const bf16x8*)&Bs[(wn * 64 + nt * 16 + col) * 32 + quad * 8];
    for (int mt = 0; mt < 4; ++mt)
      for (int nt = 0; nt < 4; ++nt)
        acc[mt][nt] = __builtin_amdgcn_mfma_f32_16x16x32_bf16(
            af[mt], bfr[nt], acc[mt][nt], 0, 0, 0);
    __syncthreads();
  }

  const int pq = n0 >> 9;  // 0=Q, 1=K, >=2 -> V
  for (int mt = 0; mt < 4; ++mt) {
    int gm0 = m0 + wm * 64 + mt * 16 + quad * 4;
    int b = gm0 >> 11, s = gm0 & (S_ - 1);
    for (int nt = 0; nt < 4; ++nt) {
      int gn = n0 + wn * 64 + nt * 16 + col;
      if (pq >= 2) {
        int vcol = gn - 1024;
        float bs = b_attn[2048 + vcol];
        int h = vcol >> 6, hd = vcol & 63;
        short4v vv;
        for (int i = 0; i < 4; ++i)
          vv[i] = (short)f2b(acc[mt][nt][i] + bs);
        size_t idx = ((((size_t)(b * H_ + h) * 64 + (s >> 5)) * 64 + hd) * 32 + (s & 31));
        *(short4v*)&Vc[idx] = vv;
      } else {
        float bs = bias2[gn];
        int gl = gn & 511;
        int h = gl >> 5, kjl = gl & 31;
        unsigned short* dst = pq ? Kjl : Qjl;
        size_t base = ((size_t)(b * H_ + h) * S_ + s) * KJL + kjl;
        for (int i = 0; i < 4; ++i)
          dst[base + (size_t)i * KJL] = f2b(acc[mt][nt][i] + bs);
      }
    }
  }
}

// ---------------- wave-independent flash attention, fixed-max softmax, K reg-dbuf ----------------
// Qjl pre-scaled by (1/8)*log2(e) (folded into weights). Vc chunk-tiled [BH][S/32][64][32].
__global__ __launch_bounds__(256, 2)
void attn_kernel(const unsigned short* __restrict__ Qjl,
                 const unsigned short* __restrict__ Kjl,
                 const unsigned short* __restrict__ Vc,
                 unsigned short* __restrict__ AO) {
  __shared__ __align__(16) unsigned short Ps[4][32 * 136];  // wave-private strips
  const int tid = threadIdx.x;
  const int lane = tid & 63, wv = tid >> 6;
  const int quad = lane >> 4, l15 = lane & 15;

  // balanced complementary mapping: co-resident pair (blk, blk+256) sums to 17 iters
  const int blk = blockIdx.x;            // 0..511
  const int xcd = blk & 7;
  const int u = blk >> 3;                // 0..63
  const int bhl = (u >> 4) & 3;
  const int g0 = u & 15;
  const int g = (u & 32) ? (15 - g0) : g0;
  const int bh = xcd * 4 + bhl;
  const int t = 63 - (g * 4 + wv);       // q-tile: rows t*32..t*32+31
  const int b = bh >> 4, h = bh & 15;

  unsigned short* Pw = &Ps[wv][0];
  const int laneK = l15 * KJL + quad * 8;
  const int laneV = l15 * 32 + quad * 8;
  const unsigned short* Kp = Kjl + (size_t)bh * S_ * KJL + laneK;
  const unsigned short* Vp = Vc + (size_t)bh * (64 * 64 * 32) + laneV;

  bf16x8 aq[2];
  for (int qn = 0; qn < 2; ++qn)
    aq[qn] = *(const bf16x8*)&Qjl[(size_t)(bh * S_ + t * 32 + qn * 16 + l15) * KJL + quad * 8];

  floatx4 o[4][2] = {};
  floatx4 psum[2] = {};
  const floatx4 zz = {0.f, 0.f, 0.f, 0.f};

  const int lastc = t >> 2;
  const int r = t & 3;

  // prologue: K fragments for chunk 0
  bf16x8 akb[2][8];
  for (int sm = 0; sm < 8; ++sm)
    akb[0][sm] = *(const bf16x8*)&Kp[sm * (16 * KJL)];
  Kp += 128 * KJL;

  for (int kt = 0; kt <= lastc; ++kt) {
    const int cur = kt & 1;
    // V frags for this chunk (consumed after softmax: long lead time)
    bf16x8 bv[4][4];
    for (int ks = 0; ks < 4; ++ks)
      for (int md = 0; md < 4; ++md)
        bv[ks][md] = *(const bf16x8*)&Vp[ks * 2048 + md * 512];
    Vp += 8192;
    // prefetch K frags for next chunk (consumed next iteration)
    if (kt < lastc) {
      for (int sm = 0; sm < 8; ++sm)
        akb[cur ^ 1][sm] = *(const bf16x8*)&Kp[sm * (16 * KJL)];
      Kp += 128 * KJL;
    }

    // QK^T swapped: A=K (m=s), B=Q (n=q) -> C[s][q], q lane-resident
    floatx4 sc[8][2];
    for (int sm = 0; sm < 8; ++sm)
      for (int qn = 0; qn < 2; ++qn)
        sc[sm][qn] = __builtin_amdgcn_mfma_f32_16x16x32_bf16(akb[cur][sm], aq[qn], zz, 0, 0, 0);

    if (kt == lastc) {                   // causal mask within final chunk
      for (int qn = 0; qn < 2; ++qn) {
        int qloc = r * 32 + qn * 16 + l15;
        for (int sm = 0; sm < 8; ++sm)
          for (int i = 0; i < 4; ++i)
            if (sm * 16 + quad * 4 + i > qloc) sc[sm][qn][i] = -1e30f;
      }
    }

    // fixed-max softmax: p = exp2(score); no serial chain
    for (int qn = 0; qn < 2; ++qn) {
      for (int sm = 0; sm < 8; ++sm) {
        float p0 = __builtin_amdgcn_exp2f(sc[sm][qn][0]);
        float p1 = __builtin_amdgcn_exp2f(sc[sm][qn][1]);
        float p2 = __builtin_amdgcn_exp2f(sc[sm][qn][2]);
        float p3 = __builtin_amdgcn_exp2f(sc[sm][qn][3]);
        psum[qn][0] += p0; psum[qn][1] += p1;
        psum[qn][2] += p2; psum[qn][3] += p3;
        uint2v pk2 = {pkbf(p0, p1), pkbf(p2, p3)};
        *(uint2v*)&Pw[(qn * 16 + l15) * 136 + sm * 16 + quad * 4] = pk2;
      }
    }

    // PV swapped: A=V^T (m=d), B=P (n=q)
    for (int ks = 0; ks < 4; ++ks) {
      bf16x8 bp[2];
      for (int qn = 0; qn < 2; ++qn)
        bp[qn] = *(const bf16x8*)&Pw[(qn * 16 + l15) * 136 + ks * 32 + quad * 8];
      for (int qn = 0; qn < 2; ++qn)
        for (int md = 0; md < 4; ++md)
          o[md][qn] = __builtin_amdgcn_mfma_f32_16x16x32_bf16(bv[ks][md], bp[qn], o[md][qn], 0, 0, 0);
    }
  }

  // epilogue
  for (int qn = 0; qn < 2; ++qn) {
    float l = psum[qn][0] + psum[qn][1] + psum[qn][2] + psum[qn][3];
    l += __shfl_xor(l, 16, 64);
    l += __shfl_xor(l, 32, 64);
    float inv = 1.f / l;
    for (int md = 0; md < 4; ++md) {
      uint2v t4 = {pkbf(o[md][qn][0] * inv, o[md][qn][1] * inv),
                   pkbf(o[md][qn][2] * inv, o[md][qn][3] * inv)};
      *(uint2v*)&Pw[(qn * 16 + l15) * 72 + md * 16 + quad * 4] = t4;
    }
  }
  {
    int q = lane >> 1, half = lane & 1;
    size_t gbase = ((size_t)(b * S_ + t * 32 + q)) * D_ + h * HD_ + half * 32;
    for (int jj = 0; jj < 4; ++jj) {
      bf16x8 v = *(const bf16x8*)&Pw[q * 72 + half * 32 + jj * 8];
      *(bf16x8*)&AO[gbase + jj * 8] = v;
    }
  }
}

// ---------------- output projection ----------------
__global__ __launch_bounds__(256, 2)
void proj_gemm_kernel(const unsigned short* __restrict__ A,
                      const unsigned short* __restrict__ Bt,
                      const float* __restrict__ bias,
                      float* __restrict__ out) {
  __shared__ __align__(16) unsigned short As[128 * 32];
  __shared__ __align__(16) unsigned short Bs[128 * 32];
  const int tid = threadIdx.x;
  const int lane = tid & 63, wv = tid >> 6;
  const int quad = lane >> 4, col = lane & 15;
  const int wm = wv >> 1, wn = wv & 1;
  const int m0 = blockIdx.y * 128, n0 = blockIdx.x * 128;

  floatx4 acc[4][4] = {};

  for (int kk = 0; kk < D_; kk += 32) {
    for (int it = 0; it < 2; ++it) {
      int c = it * 256 + tid;
      int row = c >> 2, k8 = (c & 3) << 3;
      async16(A + (size_t)(m0 + row) * D_ + kk + k8, &As[c * 8]);
      async16(Bt + (size_t)(n0 + row) * D_ + kk + k8, &Bs[c * 8]);
    }
    asm volatile("s_waitcnt vmcnt(0)" ::: "memory");
    __syncthreads();
    bf16x8 af[4], bfr[4];
    for (int mt = 0; mt < 4; ++mt)
      af[mt] = *(const bf16x8*)&As[(wm * 64 + mt * 16 + col) * 32 + quad * 8];
    for (int nt = 0; nt < 4; ++nt)
      bfr[nt] = *(const bf16x8*)&Bs[(wn * 64 + nt * 16 + col) * 32 + quad * 8];
    for (int mt = 0; mt < 4; ++mt)
      for (int nt = 0; nt < 4; ++nt)
        acc[mt][nt] = __builtin_amdgcn_mfma_f32_16x16x32_bf16(
            af[mt], bfr[nt], acc[mt][nt], 0, 0, 0);
    __syncthreads();
  }

  for (int mt = 0; mt < 4; ++mt) {
    int gm0 = m0 + wm * 64 + mt * 16 + quad * 4;
    for (int nt = 0; nt < 4; ++nt) {
      int gn = n0 + wn * 64 + nt * 16 + col;
      float bs = bias[gn];
      for (int i = 0; i < 4; ++i)
        out[(size_t)(gm0 + i) * D_ + gn] = acc[mt][nt][i] + bs;
    }
  }
}

extern "C" void kernel_launch(void* const* d_in, const int* in_sizes, int n_in,
                              void* d_out, int out_size, void* d_ws, size_t ws_size,
                              hipStream_t stream) {
  (void)in_sizes; (void)n_in; (void)out_size; (void)ws_size;
  const float* hidden = (const float*)d_in[0];
  const float* W_attn = (const float*)d_in[1];
  const float* b_attn = (const float*)d_in[2];
  const float* S_proj = (const float*)d_in[3];
  const float* W_proj = (const float*)d_in[4];
  const float* b_proj = (const float*)d_in[5];
  float* out = (float*)d_out;

  char* ws = (char*)d_ws;
  unsigned short* hB    = (unsigned short*)(ws);                    //  8 MB
  unsigned short* Bt2   = (unsigned short*)(ws + (8u << 20));       //  4 MB
  unsigned short* WpT   = (unsigned short*)(ws + (12u << 20));      //  2 MB
  float*          bias2 = (float*)         (ws + (14u << 20));      //  4 KB
  unsigned short* Qjl   = (unsigned short*)(ws + (15u << 20));      //  4 MB
  unsigned short* Kjl   = (unsigned short*)(ws + (19u << 20));      //  4 MB
  unsigned short* Vc    = (unsigned short*)(ws + (23u << 20));      //  8 MB
  unsigned short* AO    = (unsigned short*)(ws + (31u << 20));      //  8 MB

  cvt4_kernel<<<2048, 256, 0, stream>>>(hidden, hB, (B_ * S_ * D_) / 4);
  tcvt_kernel<<<dim3(32, 32), dim3(32, 8), 0, stream>>>(W_attn + 2048, Bt2 + 1024 * 1024, D_, N3);
  tcvt_kernel<<<dim3(32, 32), dim3(32, 8), 0, stream>>>(W_proj, WpT, D_, D_);
  wjl_kernel<<<128, 256, 0, stream>>>(W_attn, b_attn, S_proj, Bt2, bias2);
  qkv2_gemm_kernel<<<dim3(N2 / 128, (B_ * S_) / 128), 256, 0, stream>>>(
      hB, Bt2, b_attn, bias2, Qjl, Kjl, Vc);
  attn_kernel<<<512, 256, 0, stream>>>(Qjl, Kjl, Vc, AO);
  proj_gemm_kernel<<<dim3(D_ / 128, (B_ * S_) / 128), 256, 0, stream>>>(
      AO, WpT, b_proj, out);
}

// Round 6
// 190.478 us; speedup vs baseline: 1.1598x; 1.1598x over previous
//
#include <hip/hip_runtime.h>
#include <hip/hip_bf16.h>
#include <stdint.h>

#define B_ 2
#define S_ 2048
#define D_ 1024
#define H_ 16
#define HD_ 64
#define KJL 32
#define N3 3072
#define N2 2048

typedef __attribute__((ext_vector_type(8))) __bf16 bf16x8;
typedef __attribute__((ext_vector_type(4))) float floatx4;
typedef __attribute__((ext_vector_type(4))) short short4v;
typedef __attribute__((ext_vector_type(2))) unsigned int uint2v;

__device__ __forceinline__ unsigned short f2b(float x) {
  union { float f; unsigned u; } v; v.f = x;
  unsigned r = v.u + 0x7fffu + ((v.u >> 16) & 1u);
  return (unsigned short)(r >> 16);
}

// pack two floats to packed bf16 (round via +0x8000): hi<<16 | lo
__device__ __forceinline__ unsigned int pkbf(float lo, float hi) {
  union { float f; unsigned u; } a, b;
  a.f = lo; b.f = hi;
  return __builtin_amdgcn_perm(b.u + 0x8000u, a.u + 0x8000u, 0x07060302u);
}

__device__ __forceinline__ void async16(const void* g, void* l) {
  __builtin_amdgcn_global_load_lds((__attribute__((address_space(1))) void*)(g),
                                   (__attribute__((address_space(3))) void*)(l),
                                   16, 0, 0);
}

// ---------------- fp32 -> bf16 vectorized convert (n multiple of 4) ----------------
__global__ void cvt4_kernel(const float* __restrict__ in,
                            unsigned short* __restrict__ out, int n4) {
  int i = blockIdx.x * blockDim.x + threadIdx.x;
  int stride = gridDim.x * blockDim.x;
  for (; i < n4; i += stride) {
    float4 v = *(const float4*)(in + 4 * (size_t)i);
    short4v o = {(short)f2b(v.x), (short)f2b(v.y), (short)f2b(v.z), (short)f2b(v.w)};
    *(short4v*)(out + 4 * (size_t)i) = o;
  }
}

// ------- fp32 in[r][c] (row stride Cs) -> bf16 out[c][r] (row len R), 32x32 tiles -------
__global__ void tcvt_kernel(const float* __restrict__ in,
                            unsigned short* __restrict__ out, int R, int Cs) {
  __shared__ float t[32][33];
  int c0 = blockIdx.x * 32, r0 = blockIdx.y * 32;
  int tx = threadIdx.x, ty = threadIdx.y;
  for (int j = 0; j < 32; j += 8)
    t[ty + j][tx] = in[(size_t)(r0 + ty + j) * Cs + c0 + tx];
  __syncthreads();
  for (int j = 0; j < 32; j += 8)
    out[(size_t)(c0 + ty + j) * R + r0 + tx] = f2b(t[tx][ty + j]);
}

// ------- fused JL weights: Bt2 rows [0,512)=(Wq@Sp^T)^T*scaleQ, [512,1024)=(Wk@Sp^T)^T -------
// also bias2[n] = (b @ Sp^T) (scaled for Q). W_attn fp32 [1024][3072], Sp fp32 [32][64].
__global__ __launch_bounds__(256)
void wjl_kernel(const float* __restrict__ W_attn, const float* __restrict__ b_attn,
                const float* __restrict__ Sp, unsigned short* __restrict__ Bt2,
                float* __restrict__ bias2) {
  __shared__ float SpL[32 * 64];
  const int bid = blockIdx.x;          // 0..127
  const int part = bid >> 6;           // 0 = Q, 1 = K
  const int h = (bid >> 2) & 15;
  const int dc = bid & 3;
  const int tid = threadIdx.x;
  for (int i = tid; i < 32 * 64; i += 256) SpL[i] = Sp[i];
  __syncthreads();
  const float scale = part ? 1.0f : 0.125f * 1.44269504f;
  const int d = dc * 256 + tid;
  float w[64];
  const float* src = W_attn + (size_t)d * N3 + part * D_ + h * 64;
  for (int j = 0; j < 16; ++j) {
    float4 v = *(const float4*)&src[j * 4];
    w[j * 4 + 0] = v.x; w[j * 4 + 1] = v.y; w[j * 4 + 2] = v.z; w[j * 4 + 3] = v.w;
  }
  const int nbase = part * 512 + h * 32;
  for (int kjl = 0; kjl < 32; ++kjl) {
    float acc = 0.f;
    for (int hd = 0; hd < 64; ++hd) acc += w[hd] * SpL[kjl * 64 + hd];
    Bt2[(size_t)(nbase + kjl) * D_ + d] = f2b(acc * scale);
  }
  if (dc == 0 && tid < 32) {
    float acc = 0.f;
    for (int hd = 0; hd < 64; ++hd) acc += b_attn[part * D_ + h * 64 + hd] * SpL[tid * 64 + hd];
    bias2[nbase + tid] = acc * scale;
  }
}

// ---------------- fused qkv+JL GEMM: hB[4096,1024] @ Bt2^T -> Qjl/Kjl/Vc ----------------
// Bt2: [2048][1024] bf16 (rows 0..511 WqJl^T scaled, 512..1023 WkJl^T, 1024..2047 Wv^T)
// Qjl/Kjl: [BH][S][32] bf16; Vc: chunk-tiled [BH][S/32][64][32] bf16
__global__ __launch_bounds__(256, 2)
void qkv2_gemm_kernel(const unsigned short* __restrict__ A,
                      const unsigned short* __restrict__ Bt,
                      const float* __restrict__ b_attn,
                      const float* __restrict__ bias2,
                      unsigned short* __restrict__ Qjl,
                      unsigned short* __restrict__ Kjl,
                      unsigned short* __restrict__ Vc) {
  __shared__ __align__(16) unsigned short As[128 * 32];
  __shared__ __align__(16) unsigned short Bs[128 * 32];
  const int tid = threadIdx.x;
  const int lane = tid & 63, wv = tid >> 6;
  const int quad = lane >> 4, col = lane & 15;
  const int wm = wv >> 1, wn = wv & 1;
  const int m0 = blockIdx.y * 128, n0 = blockIdx.x * 128;

  floatx4 acc[4][4] = {};

  for (int kk = 0; kk < D_; kk += 32) {
    for (int it = 0; it < 2; ++it) {
      int c = it * 256 + tid;
      int row = c >> 2, k8 = (c & 3) << 3;
      async16(A + (size_t)(m0 + row) * D_ + kk + k8, &As[c * 8]);
      async16(Bt + (size_t)(n0 + row) * D_ + kk + k8, &Bs[c * 8]);
    }
    asm volatile("s_waitcnt vmcnt(0)" ::: "memory");
    __syncthreads();
    bf16x8 af[4], bfr[4];
    for (int mt = 0; mt < 4; ++mt)
      af[mt] = *(const bf16x8*)&As[(wm * 64 + mt * 16 + col) * 32 + quad * 8];
    for (int nt = 0; nt < 4; ++nt)
      bfr[nt] = *(const bf16x8*)&Bs[(wn * 64 + nt * 16 + col) * 32 + quad * 8];
    for (int mt = 0; mt < 4; ++mt)
      for (int nt = 0; nt < 4; ++nt)
        acc[mt][nt] = __builtin_amdgcn_mfma_f32_16x16x32_bf16(
            af[mt], bfr[nt], acc[mt][nt], 0, 0, 0);
    __syncthreads();
  }

  const int pq = n0 >> 9;  // 0=Q, 1=K, >=2 -> V
  for (int mt = 0; mt < 4; ++mt) {
    int gm0 = m0 + wm * 64 + mt * 16 + quad * 4;
    int b = gm0 >> 11, s = gm0 & (S_ - 1);
    for (int nt = 0; nt < 4; ++nt) {
      int gn = n0 + wn * 64 + nt * 16 + col;
      if (pq >= 2) {
        int vcol = gn - 1024;
        float bs = b_attn[2048 + vcol];
        int h = vcol >> 6, hd = vcol & 63;
        short4v vv;
        for (int i = 0; i < 4; ++i)
          vv[i] = (short)f2b(acc[mt][nt][i] + bs);
        size_t idx = ((((size_t)(b * H_ + h) * 64 + (s >> 5)) * 64 + hd) * 32 + (s & 31));
        *(short4v*)&Vc[idx] = vv;
      } else {
        float bs = bias2[gn];
        int gl = gn & 511;
        int h = gl >> 5, kjl = gl & 31;
        unsigned short* dst = pq ? Kjl : Qjl;
        size_t base = ((size_t)(b * H_ + h) * S_ + s) * KJL + kjl;
        for (int i = 0; i < 4; ++i)
          dst[base + (size_t)i * KJL] = f2b(acc[mt][nt][i] + bs);
      }
    }
  }
}

// ---------------- wave-independent flash attention, fixed-max softmax ----------------
// (round-4 inner loop: K/V fragment loads issued at iteration top, NO dynamically
//  indexed register arrays — the round-5 K reg-dbuf spilled to scratch: WRITE_SIZE
//  8 MB -> 141 MB. Do not reintroduce runtime-indexed register buffers.)
// Qjl pre-scaled by (1/8)*log2(e) (folded into weights). Vc chunk-tiled [BH][S/32][64][32].
__global__ __launch_bounds__(256, 2)
void attn_kernel(const unsigned short* __restrict__ Qjl,
                 const unsigned short* __restrict__ Kjl,
                 const unsigned short* __restrict__ Vc,
                 unsigned short* __restrict__ AO) {
  __shared__ __align__(16) unsigned short Ps[4][32 * 136];  // wave-private strips
  const int tid = threadIdx.x;
  const int lane = tid & 63, wv = tid >> 6;
  const int quad = lane >> 4, l15 = lane & 15;

  // balanced complementary mapping: co-resident pair (blk, blk+256) sums to 17 iters
  const int blk = blockIdx.x;            // 0..511
  const int xcd = blk & 7;
  const int u = blk >> 3;                // 0..63
  const int bhl = (u >> 4) & 3;
  const int g0 = u & 15;
  const int g = (u & 32) ? (15 - g0) : g0;
  const int bh = xcd * 4 + bhl;
  const int t = 63 - (g * 4 + wv);       // q-tile: rows t*32..t*32+31
  const int b = bh >> 4, h = bh & 15;

  unsigned short* Pw = &Ps[wv][0];
  const int laneK = l15 * KJL + quad * 8;
  const int laneV = l15 * 32 + quad * 8;
  const unsigned short* Kp = Kjl + (size_t)bh * S_ * KJL + laneK;
  const unsigned short* Vp = Vc + (size_t)bh * (64 * 64 * 32) + laneV;

  bf16x8 aq[2];
  for (int qn = 0; qn < 2; ++qn)
    aq[qn] = *(const bf16x8*)&Qjl[(size_t)(bh * S_ + t * 32 + qn * 16 + l15) * KJL + quad * 8];

  floatx4 o[4][2] = {};
  floatx4 psum[2] = {};
  const floatx4 zz = {0.f, 0.f, 0.f, 0.f};

  const int lastc = t >> 2;
  const int r = t & 3;

  for (int kt = 0; kt <= lastc; ++kt) {
    // --- issue all VMEM up front: K frags (consumed first), then V frags ---
    bf16x8 ak[8];
    for (int sm = 0; sm < 8; ++sm)
      ak[sm] = *(const bf16x8*)&Kp[sm * (16 * KJL)];
    bf16x8 bv[4][4];                     // bv[ks][md]
    for (int ks = 0; ks < 4; ++ks)
      for (int md = 0; md < 4; ++md)
        bv[ks][md] = *(const bf16x8*)&Vp[ks * 2048 + md * 512];
    Kp += 128 * KJL;
    Vp += 8192;

    // --- QK^T swapped: A=K (m=s), B=Q (n=q) -> C[s][q], q lane-resident ---
    floatx4 sc[8][2];
    for (int sm = 0; sm < 8; ++sm)
      for (int qn = 0; qn < 2; ++qn)
        sc[sm][qn] = __builtin_amdgcn_mfma_f32_16x16x32_bf16(ak[sm], aq[qn], zz, 0, 0, 0);

    if (kt == lastc) {                   // causal mask within final chunk
      for (int qn = 0; qn < 2; ++qn) {
        int qloc = r * 32 + qn * 16 + l15;
        for (int sm = 0; sm < 8; ++sm)
          for (int i = 0; i < 4; ++i)
            if (sm * 16 + quad * 4 + i > qloc) sc[sm][qn][i] = -1e30f;
      }
    }

    // --- fixed-max softmax: p = exp2(score); independent ops, no serial chain ---
    for (int qn = 0; qn < 2; ++qn) {
      for (int sm = 0; sm < 8; ++sm) {
        float p0 = __builtin_amdgcn_exp2f(sc[sm][qn][0]);
        float p1 = __builtin_amdgcn_exp2f(sc[sm][qn][1]);
        float p2 = __builtin_amdgcn_exp2f(sc[sm][qn][2]);
        float p3 = __builtin_amdgcn_exp2f(sc[sm][qn][3]);
        psum[qn][0] += p0; psum[qn][1] += p1;
        psum[qn][2] += p2; psum[qn][3] += p3;
        uint2v pk2 = {pkbf(p0, p1), pkbf(p2, p3)};
        *(uint2v*)&Pw[(qn * 16 + l15) * 136 + sm * 16 + quad * 4] = pk2;
      }
    }

    // --- PV swapped: A=V^T (m=d), B=P (n=q); bp via wave-private LDS (in-order) ---
    for (int ks = 0; ks < 4; ++ks) {
      bf16x8 bp[2];
      for (int qn = 0; qn < 2; ++qn)
        bp[qn] = *(const bf16x8*)&Pw[(qn * 16 + l15) * 136 + ks * 32 + quad * 8];
      for (int qn = 0; qn < 2; ++qn)
        for (int md = 0; md < 4; ++md)
          o[md][qn] = __builtin_amdgcn_mfma_f32_16x16x32_bf16(bv[ks][md], bp[qn], o[md][qn], 0, 0, 0);
    }
  }

  // --- epilogue: reduce row sums, scale, transpose via LDS, coalesced store ---
  for (int qn = 0; qn < 2; ++qn) {
    float l = psum[qn][0] + psum[qn][1] + psum[qn][2] + psum[qn][3];
    l += __shfl_xor(l, 16, 64);
    l += __shfl_xor(l, 32, 64);
    float inv = 1.f / l;
    for (int md = 0; md < 4; ++md) {
      uint2v t4 = {pkbf(o[md][qn][0] * inv, o[md][qn][1] * inv),
                   pkbf(o[md][qn][2] * inv, o[md][qn][3] * inv)};
      *(uint2v*)&Pw[(qn * 16 + l15) * 72 + md * 16 + quad * 4] = t4;
    }
  }
  {
    int q = lane >> 1, half = lane & 1;
    size_t gbase = ((size_t)(b * S_ + t * 32 + q)) * D_ + h * HD_ + half * 32;
    for (int jj = 0; jj < 4; ++jj) {
      bf16x8 v = *(const bf16x8*)&Pw[q * 72 + half * 32 + jj * 8];
      *(bf16x8*)&AO[gbase + jj * 8] = v;
    }
  }
}

// ---------------- output projection ----------------
__global__ __launch_bounds__(256, 2)
void proj_gemm_kernel(const unsigned short* __restrict__ A,
                      const unsigned short* __restrict__ Bt,
                      const float* __restrict__ bias,
                      float* __restrict__ out) {
  __shared__ __align__(16) unsigned short As[128 * 32];
  __shared__ __align__(16) unsigned short Bs[128 * 32];
  const int tid = threadIdx.x;
  const int lane = tid & 63, wv = tid >> 6;
  const int quad = lane >> 4, col = lane & 15;
  const int wm = wv >> 1, wn = wv & 1;
  const int m0 = blockIdx.y * 128, n0 = blockIdx.x * 128;

  floatx4 acc[4][4] = {};

  for (int kk = 0; kk < D_; kk += 32) {
    for (int it = 0; it < 2; ++it) {
      int c = it * 256 + tid;
      int row = c >> 2, k8 = (c & 3) << 3;
      async16(A + (size_t)(m0 + row) * D_ + kk + k8, &As[c * 8]);
      async16(Bt + (size_t)(n0 + row) * D_ + kk + k8, &Bs[c * 8]);
    }
    asm volatile("s_waitcnt vmcnt(0)" ::: "memory");
    __syncthreads();
    bf16x8 af[4], bfr[4];
    for (int mt = 0; mt < 4; ++mt)
      af[mt] = *(const bf16x8*)&As[(wm * 64 + mt * 16 + col) * 32 + quad * 8];
    for (int nt = 0; nt < 4; ++nt)
      bfr[nt] = *(const bf16x8*)&Bs[(wn * 64 + nt * 16 + col) * 32 + quad * 8];
    for (int mt = 0; mt < 4; ++mt)
      for (int nt = 0; nt < 4; ++nt)
        acc[mt][nt] = __builtin_amdgcn_mfma_f32_16x16x32_bf16(
            af[mt], bfr[nt], acc[mt][nt], 0, 0, 0);
    __syncthreads();
  }

  for (int mt = 0; mt < 4; ++mt) {
    int gm0 = m0 + wm * 64 + mt * 16 + quad * 4;
    for (int nt = 0; nt < 4; ++nt) {
      int gn = n0 + wn * 64 + nt * 16 + col;
      float bs = bias[gn];
      for (int i = 0; i < 4; ++i)
        out[(size_t)(gm0 + i) * D_ + gn] = acc[mt][nt][i] + bs;
    }
  }
}

extern "C" void kernel_launch(void* const* d_in, const int* in_sizes, int n_in,
                              void* d_out, int out_size, void* d_ws, size_t ws_size,
                              hipStream_t stream) {
  (void)in_sizes; (void)n_in; (void)out_size; (void)ws_size;
  const float* hidden = (const float*)d_in[0];
  const float* W_attn = (const float*)d_in[1];
  const float* b_attn = (const float*)d_in[2];
  const float* S_proj = (const float*)d_in[3];
  const float* W_proj = (const float*)d_in[4];
  const float* b_proj = (const float*)d_in[5];
  float* out = (float*)d_out;

  char* ws = (char*)d_ws;
  unsigned short* hB    = (unsigned short*)(ws);                    //  8 MB
  unsigned short* Bt2   = (unsigned short*)(ws + (8u << 20));       //  4 MB
  unsigned short* WpT   = (unsigned short*)(ws + (12u << 20));      //  2 MB
  float*          bias2 = (float*)         (ws + (14u << 20));      //  4 KB
  unsigned short* Qjl   = (unsigned short*)(ws + (15u << 20));      //  4 MB
  unsigned short* Kjl   = (unsigned short*)(ws + (19u << 20));      //  4 MB
  unsigned short* Vc    = (unsigned short*)(ws + (23u << 20));      //  8 MB
  unsigned short* AO    = (unsigned short*)(ws + (31u << 20));      //  8 MB

  cvt4_kernel<<<2048, 256, 0, stream>>>(hidden, hB, (B_ * S_ * D_) / 4);
  tcvt_kernel<<<dim3(32, 32), dim3(32, 8), 0, stream>>>(W_attn + 2048, Bt2 + 1024 * 1024, D_, N3);
  tcvt_kernel<<<dim3(32, 32), dim3(32, 8), 0, stream>>>(W_proj, WpT, D_, D_);
  wjl_kernel<<<128, 256, 0, stream>>>(W_attn, b_attn, S_proj, Bt2, bias2);
  qkv2_gemm_kernel<<<dim3(N2 / 128, (B_ * S_) / 128), 256, 0, stream>>>(
      hB, Bt2, b_attn, bias2, Qjl, Kjl, Vc);
  attn_kernel<<<512, 256, 0, stream>>>(Qjl, Kjl, Vc, AO);
  proj_gemm_kernel<<<dim3(D_ / 128, (B_ * S_) / 128), 256, 0, stream>>>(
      AO, WpT, b_proj, out);
}

// Round 7
// 187.588 us; speedup vs baseline: 1.1777x; 1.0154x over previous
//
#include <hip/hip_runtime.h>
#include <hip/hip_bf16.h>
#include <stdint.h>

#define B_ 2
#define S_ 2048
#define D_ 1024
#define H_ 16
#define HD_ 64
#define KJL 32
#define N3 3072
#define N2 2048

typedef __attribute__((ext_vector_type(8))) __bf16 bf16x8;
typedef __attribute__((ext_vector_type(4))) float floatx4;
typedef __attribute__((ext_vector_type(4))) short short4v;
typedef __attribute__((ext_vector_type(2))) unsigned int uint2v;

__device__ __forceinline__ unsigned short f2b(float x) {
  union { float f; unsigned u; } v; v.f = x;
  unsigned r = v.u + 0x7fffu + ((v.u >> 16) & 1u);
  return (unsigned short)(r >> 16);
}

// pack two floats to packed bf16 (round via +0x8000): hi<<16 | lo
__device__ __forceinline__ unsigned int pkbf(float lo, float hi) {
  union { float f; unsigned u; } a, b;
  a.f = lo; b.f = hi;
  return __builtin_amdgcn_perm(b.u + 0x8000u, a.u + 0x8000u, 0x07060302u);
}

__device__ __forceinline__ void async16(const void* g, void* l) {
  __builtin_amdgcn_global_load_lds((__attribute__((address_space(1))) void*)(g),
                                   (__attribute__((address_space(3))) void*)(l),
                                   16, 0, 0);
}

// ---------------- fused prep: cvt4 | tcvt(V cols) | tcvt(W_proj) | wjl ----------------
// blocks [0,512): hidden fp32 -> hB bf16 (grid-stride float4)
// blocks [512,1536): W_attn V-slice [1024 rows x cols 2048..3071] -> Bt2[1024..2047][1024]
// blocks [1536,2560): W_proj -> WpT transpose-convert
// blocks [2560,2688): JL-fused Q/K weights + bias2
__global__ __launch_bounds__(256)
void prep_kernel(const float* __restrict__ hidden, unsigned short* __restrict__ hB,
                 const float* __restrict__ W_attn, const float* __restrict__ b_attn,
                 const float* __restrict__ Sp, const float* __restrict__ W_proj,
                 unsigned short* __restrict__ Bt2, unsigned short* __restrict__ WpT,
                 float* __restrict__ bias2) {
  __shared__ float shmem[2048];
  const int bid = blockIdx.x;
  const int tid = threadIdx.x;

  if (bid < 512) {                      // ---- cvt4: hidden -> hB ----
    const int n4 = (B_ * S_ * D_) / 4;
    int i = bid * 256 + tid;
    for (; i < n4; i += 512 * 256) {
      float4 v = *(const float4*)(hidden + 4 * (size_t)i);
      short4v o = {(short)f2b(v.x), (short)f2b(v.y), (short)f2b(v.z), (short)f2b(v.w)};
      *(short4v*)(hB + 4 * (size_t)i) = o;
    }
  } else if (bid < 2560) {              // ---- tcvt: 32x32 transpose-convert tiles ----
    const float* in;
    unsigned short* out;
    int Cs, local;
    if (bid < 1536) { local = bid - 512;  in = W_attn + 2048; out = Bt2 + 1024 * 1024; Cs = N3; }
    else            { local = bid - 1536; in = W_proj;        out = WpT;               Cs = D_; }
    float (*t)[33] = (float(*)[33])shmem;
    int c0 = (local & 31) * 32, r0 = (local >> 5) * 32;
    int tx = tid & 31, ty = tid >> 5;
    for (int j = 0; j < 32; j += 8)
      t[ty + j][tx] = in[(size_t)(r0 + ty + j) * Cs + c0 + tx];
    __syncthreads();
    for (int j = 0; j < 32; j += 8)
      out[(size_t)(c0 + ty + j) * D_ + r0 + tx] = f2b(t[tx][ty + j]);
  } else {                              // ---- wjl: fused JL weights ----
    const int lb = bid - 2560;          // 0..127
    const int part = lb >> 6;           // 0 = Q, 1 = K
    const int h = (lb >> 2) & 15;
    const int dc = lb & 3;
    for (int i = tid; i < 32 * 64; i += 256) shmem[i] = Sp[i];
    __syncthreads();
    const float scale = part ? 1.0f : 0.125f * 1.44269504f;
    const int d = dc * 256 + tid;
    float w[64];
    const float* src = W_attn + (size_t)d * N3 + part * D_ + h * 64;
    for (int j = 0; j < 16; ++j) {
      float4 v = *(const float4*)&src[j * 4];
      w[j * 4 + 0] = v.x; w[j * 4 + 1] = v.y; w[j * 4 + 2] = v.z; w[j * 4 + 3] = v.w;
    }
    const int nbase = part * 512 + h * 32;
    for (int kjl = 0; kjl < 32; ++kjl) {
      float acc = 0.f;
      for (int hd = 0; hd < 64; ++hd) acc += w[hd] * shmem[kjl * 64 + hd];
      Bt2[(size_t)(nbase + kjl) * D_ + d] = f2b(acc * scale);
    }
    if (dc == 0 && tid < 32) {
      float acc = 0.f;
      for (int hd = 0; hd < 64; ++hd) acc += b_attn[part * D_ + h * 64 + hd] * shmem[tid * 64 + hd];
      bias2[nbase + tid] = acc * scale;
    }
  }
}

// ---------------- fused qkv+JL GEMM: hB[4096,1024] @ Bt2^T -> Qjl/Kjl/Vc ----------------
// Bt2: [2048][1024] bf16 (rows 0..511 WqJl^T scaled, 512..1023 WkJl^T, 1024..2047 Wv^T)
// Qjl/Kjl: [BH][S][32] bf16; Vc: chunk-tiled [BH][S/32][64][32] bf16
__global__ __launch_bounds__(256, 2)
void qkv2_gemm_kernel(const unsigned short* __restrict__ A,
                      const unsigned short* __restrict__ Bt,
                      const float* __restrict__ b_attn,
                      const float* __restrict__ bias2,
                      unsigned short* __restrict__ Qjl,
                      unsigned short* __restrict__ Kjl,
                      unsigned short* __restrict__ Vc) {
  __shared__ __align__(16) unsigned short As[128 * 32];
  __shared__ __align__(16) unsigned short Bs[128 * 32];
  const int tid = threadIdx.x;
  const int lane = tid & 63, wv = tid >> 6;
  const int quad = lane >> 4, col = lane & 15;
  const int wm = wv >> 1, wn = wv & 1;
  const int m0 = blockIdx.y * 128, n0 = blockIdx.x * 128;

  floatx4 acc[4][4] = {};

  for (int kk = 0; kk < D_; kk += 32) {
    for (int it = 0; it < 2; ++it) {
      int c = it * 256 + tid;
      int row = c >> 2, k8 = (c & 3) << 3;
      async16(A + (size_t)(m0 + row) * D_ + kk + k8, &As[c * 8]);
      async16(Bt + (size_t)(n0 + row) * D_ + kk + k8, &Bs[c * 8]);
    }
    asm volatile("s_waitcnt vmcnt(0)" ::: "memory");
    __syncthreads();
    bf16x8 af[4], bfr[4];
    for (int mt = 0; mt < 4; ++mt)
      af[mt] = *(const bf16x8*)&As[(wm * 64 + mt * 16 + col) * 32 + quad * 8];
    for (int nt = 0; nt < 4; ++nt)
      bfr[nt] = *(const bf16x8*)&Bs[(wn * 64 + nt * 16 + col) * 32 + quad * 8];
    for (int mt = 0; mt < 4; ++mt)
      for (int nt = 0; nt < 4; ++nt)
        acc[mt][nt] = __builtin_amdgcn_mfma_f32_16x16x32_bf16(
            af[mt], bfr[nt], acc[mt][nt], 0, 0, 0);
    __syncthreads();
  }

  const int pq = n0 >> 9;  // 0=Q, 1=K, >=2 -> V
  for (int mt = 0; mt < 4; ++mt) {
    int gm0 = m0 + wm * 64 + mt * 16 + quad * 4;
    int b = gm0 >> 11, s = gm0 & (S_ - 1);
    for (int nt = 0; nt < 4; ++nt) {
      int gn = n0 + wn * 64 + nt * 16 + col;
      if (pq >= 2) {
        int vcol = gn - 1024;
        float bs = b_attn[2048 + vcol];
        int h = vcol >> 6, hd = vcol & 63;
        short4v vv;
        for (int i = 0; i < 4; ++i)
          vv[i] = (short)f2b(acc[mt][nt][i] + bs);
        size_t idx = ((((size_t)(b * H_ + h) * 64 + (s >> 5)) * 64 + hd) * 32 + (s & 31));
        *(short4v*)&Vc[idx] = vv;
      } else {
        float bs = bias2[gn];
        int gl = gn & 511;
        int h = gl >> 5, kjl = gl & 31;
        unsigned short* dst = pq ? Kjl : Qjl;
        size_t base = ((size_t)(b * H_ + h) * S_ + s) * KJL + kjl;
        for (int i = 0; i < 4; ++i)
          dst[base + (size_t)i * KJL] = f2b(acc[mt][nt][i] + bs);
      }
    }
  }
}

// ---------------- wave-independent flash attention, fixed-max softmax ----------------
// (round-4 inner loop: K/V fragment loads issued at iteration top, NO dynamically
//  indexed register arrays — a runtime-indexed K reg-dbuf spilled to scratch in
//  round 5: WRITE_SIZE 8 MB -> 141 MB. Do not reintroduce.)
// Qjl pre-scaled by (1/8)*log2(e) (folded into weights). Vc chunk-tiled [BH][S/32][64][32].
__global__ __launch_bounds__(256, 2)
void attn_kernel(const unsigned short* __restrict__ Qjl,
                 const unsigned short* __restrict__ Kjl,
                 const unsigned short* __restrict__ Vc,
                 unsigned short* __restrict__ AO) {
  __shared__ __align__(16) unsigned short Ps[4][32 * 136];  // wave-private strips
  const int tid = threadIdx.x;
  const int lane = tid & 63, wv = tid >> 6;
  const int quad = lane >> 4, l15 = lane & 15;

  // balanced complementary mapping: co-resident pair (blk, blk+256) sums to 17 iters
  const int blk = blockIdx.x;            // 0..511
  const int xcd = blk & 7;
  const int u = blk >> 3;                // 0..63
  const int bhl = (u >> 4) & 3;
  const int g0 = u & 15;
  const int g = (u & 32) ? (15 - g0) : g0;
  const int bh = xcd * 4 + bhl;
  const int t = 63 - (g * 4 + wv);       // q-tile: rows t*32..t*32+31
  const int b = bh >> 4, h = bh & 15;

  unsigned short* Pw = &Ps[wv][0];
  const int laneK = l15 * KJL + quad * 8;
  const int laneV = l15 * 32 + quad * 8;
  const unsigned short* Kp = Kjl + (size_t)bh * S_ * KJL + laneK;
  const unsigned short* Vp = Vc + (size_t)bh * (64 * 64 * 32) + laneV;

  bf16x8 aq[2];
  for (int qn = 0; qn < 2; ++qn)
    aq[qn] = *(const bf16x8*)&Qjl[(size_t)(bh * S_ + t * 32 + qn * 16 + l15) * KJL + quad * 8];

  floatx4 o[4][2] = {};
  floatx4 psum[2] = {};
  const floatx4 zz = {0.f, 0.f, 0.f, 0.f};

  const int lastc = t >> 2;
  const int r = t & 3;

  for (int kt = 0; kt <= lastc; ++kt) {
    // --- issue all VMEM up front: K frags (consumed first), then V frags ---
    bf16x8 ak[8];
    for (int sm = 0; sm < 8; ++sm)
      ak[sm] = *(const bf16x8*)&Kp[sm * (16 * KJL)];
    bf16x8 bv[4][4];                     // bv[ks][md]
    for (int ks = 0; ks < 4; ++ks)
      for (int md = 0; md < 4; ++md)
        bv[ks][md] = *(const bf16x8*)&Vp[ks * 2048 + md * 512];
    Kp += 128 * KJL;
    Vp += 8192;

    // --- QK^T swapped: A=K (m=s), B=Q (n=q) -> C[s][q], q lane-resident ---
    floatx4 sc[8][2];
    for (int sm = 0; sm < 8; ++sm)
      for (int qn = 0; qn < 2; ++qn)
        sc[sm][qn] = __builtin_amdgcn_mfma_f32_16x16x32_bf16(ak[sm], aq[qn], zz, 0, 0, 0);

    if (kt == lastc) {                   // causal mask within final chunk
      for (int qn = 0; qn < 2; ++qn) {
        int qloc = r * 32 + qn * 16 + l15;
        for (int sm = 0; sm < 8; ++sm)
          for (int i = 0; i < 4; ++i)
            if (sm * 16 + quad * 4 + i > qloc) sc[sm][qn][i] = -1e30f;
      }
    }

    // --- fixed-max softmax: p = exp2(score); independent ops, no serial chain ---
    for (int qn = 0; qn < 2; ++qn) {
      for (int sm = 0; sm < 8; ++sm) {
        float p0 = __builtin_amdgcn_exp2f(sc[sm][qn][0]);
        float p1 = __builtin_amdgcn_exp2f(sc[sm][qn][1]);
        float p2 = __builtin_amdgcn_exp2f(sc[sm][qn][2]);
        float p3 = __builtin_amdgcn_exp2f(sc[sm][qn][3]);
        psum[qn][0] += p0; psum[qn][1] += p1;
        psum[qn][2] += p2; psum[qn][3] += p3;
        uint2v pk2 = {pkbf(p0, p1), pkbf(p2, p3)};
        *(uint2v*)&Pw[(qn * 16 + l15) * 136 + sm * 16 + quad * 4] = pk2;
      }
    }

    // --- PV swapped: A=V^T (m=d), B=P (n=q); bp via wave-private LDS (in-order) ---
    for (int ks = 0; ks < 4; ++ks) {
      bf16x8 bp[2];
      for (int qn = 0; qn < 2; ++qn)
        bp[qn] = *(const bf16x8*)&Pw[(qn * 16 + l15) * 136 + ks * 32 + quad * 8];
      for (int qn = 0; qn < 2; ++qn)
        for (int md = 0; md < 4; ++md)
          o[md][qn] = __builtin_amdgcn_mfma_f32_16x16x32_bf16(bv[ks][md], bp[qn], o[md][qn], 0, 0, 0);
    }
  }

  // --- epilogue: reduce row sums, scale, transpose via LDS, coalesced store ---
  for (int qn = 0; qn < 2; ++qn) {
    float l = psum[qn][0] + psum[qn][1] + psum[qn][2] + psum[qn][3];
    l += __shfl_xor(l, 16, 64);
    l += __shfl_xor(l, 32, 64);
    float inv = 1.f / l;
    for (int md = 0; md < 4; ++md) {
      uint2v t4 = {pkbf(o[md][qn][0] * inv, o[md][qn][1] * inv),
                   pkbf(o[md][qn][2] * inv, o[md][qn][3] * inv)};
      *(uint2v*)&Pw[(qn * 16 + l15) * 72 + md * 16 + quad * 4] = t4;
    }
  }
  {
    int q = lane >> 1, half = lane & 1;
    size_t gbase = ((size_t)(b * S_ + t * 32 + q)) * D_ + h * HD_ + half * 32;
    for (int jj = 0; jj < 4; ++jj) {
      bf16x8 v = *(const bf16x8*)&Pw[q * 72 + half * 32 + jj * 8];
      *(bf16x8*)&AO[gbase + jj * 8] = v;
    }
  }
}

// ---------------- output projection: 64x128 tiles (512 blocks = 2/CU) ----------------
__global__ __launch_bounds__(256, 2)
void proj_gemm_kernel(const unsigned short* __restrict__ A,
                      const unsigned short* __restrict__ Bt,
                      const float* __restrict__ bias,
                      float* __restrict__ out) {
  __shared__ __align__(16) unsigned short As[64 * 32];
  __shared__ __align__(16) unsigned short Bs[128 * 32];
  const int tid = threadIdx.x;
  const int lane = tid & 63, wv = tid >> 6;
  const int quad = lane >> 4, col = lane & 15;
  const int wm = wv >> 1, wn = wv & 1;
  const int m0 = blockIdx.y * 64, n0 = blockIdx.x * 128;

  floatx4 acc[2][4] = {};

  for (int kk = 0; kk < D_; kk += 32) {
    {
      int c = tid;                       // A tile: 64 rows x 32 k = one 16B chunk/thread
      int row = c >> 2, k8 = (c & 3) << 3;
      async16(A + (size_t)(m0 + row) * D_ + kk + k8, &As[c * 8]);
    }
    for (int it = 0; it < 2; ++it) {     // B tile: 128 rows x 32 k
      int c = it * 256 + tid;
      int row = c >> 2, k8 = (c & 3) << 3;
      async16(Bt + (size_t)(n0 + row) * D_ + kk + k8, &Bs[c * 8]);
    }
    asm volatile("s_waitcnt vmcnt(0)" ::: "memory");
    __syncthreads();
    bf16x8 af[2], bfr[4];
    for (int mt = 0; mt < 2; ++mt)
      af[mt] = *(const bf16x8*)&As[(wm * 32 + mt * 16 + col) * 32 + quad * 8];
    for (int nt = 0; nt < 4; ++nt)
      bfr[nt] = *(const bf16x8*)&Bs[(wn * 64 + nt * 16 + col) * 32 + quad * 8];
    for (int mt = 0; mt < 2; ++mt)
      for (int nt = 0; nt < 4; ++nt)
        acc[mt][nt] = __builtin_amdgcn_mfma_f32_16x16x32_bf16(
            af[mt], bfr[nt], acc[mt][nt], 0, 0, 0);
    __syncthreads();
  }

  for (int mt = 0; mt < 2; ++mt) {
    int gm0 = m0 + wm * 32 + mt * 16 + quad * 4;
    for (int nt = 0; nt < 4; ++nt) {
      int gn = n0 + wn * 64 + nt * 16 + col;
      float bs = bias[gn];
      for (int i = 0; i < 4; ++i)
        out[(size_t)(gm0 + i) * D_ + gn] = acc[mt][nt][i] + bs;
    }
  }
}

extern "C" void kernel_launch(void* const* d_in, const int* in_sizes, int n_in,
                              void* d_out, int out_size, void* d_ws, size_t ws_size,
                              hipStream_t stream) {
  (void)in_sizes; (void)n_in; (void)out_size; (void)ws_size;
  const float* hidden = (const float*)d_in[0];
  const float* W_attn = (const float*)d_in[1];
  const float* b_attn = (const float*)d_in[2];
  const float* S_proj = (const float*)d_in[3];
  const float* W_proj = (const float*)d_in[4];
  const float* b_proj = (const float*)d_in[5];
  float* out = (float*)d_out;

  char* ws = (char*)d_ws;
  unsigned short* hB    = (unsigned short*)(ws);                    //  8 MB
  unsigned short* Bt2   = (unsigned short*)(ws + (8u << 20));       //  4 MB
  unsigned short* WpT   = (unsigned short*)(ws + (12u << 20));      //  2 MB
  float*          bias2 = (float*)         (ws + (14u << 20));      //  4 KB
  unsigned short* Qjl   = (unsigned short*)(ws + (15u << 20));      //  4 MB
  unsigned short* Kjl   = (unsigned short*)(ws + (19u << 20));      //  4 MB
  unsigned short* Vc    = (unsigned short*)(ws + (23u << 20));      //  8 MB
  unsigned short* AO    = (unsigned short*)(ws + (31u << 20));      //  8 MB

  prep_kernel<<<2688, 256, 0, stream>>>(hidden, hB, W_attn, b_attn, S_proj,
                                        W_proj, Bt2, WpT, bias2);
  qkv2_gemm_kernel<<<dim3(N2 / 128, (B_ * S_) / 128), 256, 0, stream>>>(
      hB, Bt2, b_attn, bias2, Qjl, Kjl, Vc);
  attn_kernel<<<512, 256, 0, stream>>>(Qjl, Kjl, Vc, AO);
  proj_gemm_kernel<<<dim3(D_ / 128, (B_ * S_) / 64), 256, 0, stream>>>(
      AO, WpT, b_proj, out);
}